// Round 1
// 1557.733 us; speedup vs baseline: 2.1502x; 2.1502x over previous
//
#include <hip/hip_runtime.h>
#include <math.h>

typedef _Float16 f16;
typedef _Float16 f16x8 __attribute__((ext_vector_type(8)));
typedef _Float16 f16x4 __attribute__((ext_vector_type(4)));
typedef float    f32x4 __attribute__((ext_vector_type(4)));

#define NB 16
#define NP 2048
#define NH 2048
#define ND 1024
#define MT 32          // premise rows per block
#define NT 64          // hypothesis cols per iteration
#define SCALE 0.03125f // 1/sqrt(1024), exact power of 2 -> folded into Q f16

// ---------------------------------------------------------------------------
// Prep: hypothesis fp32 -> f16, two layouts:
//   KVh[b][h][d]  (QK^T B-operand: contraction along d, rows contiguous in d)
//   KVt[b][d][h]  (PV   B-operand: contraction along h, rows contiguous in h)
// 64x64 tiles, LDS transpose. Memory-bound; ~384MB total traffic.
// ---------------------------------------------------------------------------
__global__ __launch_bounds__(256)
void prep(const float* __restrict__ KV, f16* __restrict__ KVh, f16* __restrict__ KVt)
{
  __shared__ f16 tile[64][68];           // +4 f16 pad
  const int bb = blockIdx.z;
  const int h0 = blockIdx.y << 6;
  const int d0 = blockIdx.x << 6;
  const int tid = threadIdx.x;
  const int r0 = tid >> 4;
  const int c0 = (tid & 15) << 2;
#pragma unroll
  for (int i = 0; i < 4; ++i) {
    const int r = r0 + (i << 4);
    f32x4 v = *(const f32x4*)(KV + ((size_t)(bb * NH + h0 + r)) * ND + d0 + c0);
    f16x4 hv;
    hv[0] = (f16)v[0]; hv[1] = (f16)v[1]; hv[2] = (f16)v[2]; hv[3] = (f16)v[3];
    *(f16x4*)(KVh + ((size_t)(bb * NH + h0 + r)) * ND + d0 + c0) = hv;
    *(f16x4*)&tile[r][c0] = hv;
  }
  __syncthreads();
#pragma unroll
  for (int i = 0; i < 4; ++i) {
    const int dr = r0 + (i << 4);
    f16x4 hv;
#pragma unroll
    for (int j = 0; j < 4; ++j) hv[j] = tile[c0 + j][dr];
    *(f16x4*)(KVt + ((size_t)(bb * ND + d0 + dr)) * NH + h0 + c0) = hv;
  }
}

// ---------------------------------------------------------------------------
// Main: flash-style uni-attention. MFMA 16x16x32 f16 layouts (HW-verified):
//   A: m = lane&15, k = (lane>>4)*8 + j ;  B: n = lane&15, k = (lane>>4)*8 + j
//   C/D: col = lane&15, row = (lane>>4)*4 + reg
// Q tile: converted ONCE per block to LDS f16 (scaled), XOR-swizzled chunks.
// K frags: 16B loads from KVh. V frags: 16B loads from KVt (pre-transposed).
// ---------------------------------------------------------------------------
__global__ __launch_bounds__(256, 2)
void uniattn(const float* __restrict__ Q,   const float* __restrict__ PM,
             const f16*   __restrict__ KVh, const f16*   __restrict__ KVt,
             const float* __restrict__ HM,  float* __restrict__ OUT)
{
  const int bid  = blockIdx.x;
  const int b    = bid >> 6;           // 64 p-tiles per batch
  const int p0   = (bid & 63) * MT;
  const int tid  = threadIdx.x;
  const int w    = tid >> 6;           // wave 0..3
  const int lane = tid & 63;
  const int qd   = lane >> 4;          // quad 0..3
  const int c16  = lane & 15;
  const int rt   = w & 1;              // S row-tile this wave computes (phase A)
  const int wp   = w >> 1;             // S col-pair group (phase A)

  // ---- premise-mask block skip (mask is monotone: arange < len) ----
  if (PM[(size_t)b * NP + p0] == 0.0f) {
    float* ob = OUT + ((size_t)b * NP + p0) * ND;
    const f32x4 z = {0.f, 0.f, 0.f, 0.f};
#pragma unroll
    for (int i = 0; i < 32; ++i)
      *(f32x4*)(ob + (size_t)((i << 8) + tid) * 4) = z;
    return;
  }

  __shared__ f16 Qs[32 * 1024];        // 64KB: Q tile, f16, scaled, swizzled
  __shared__ float pm_s[2][2][16];     // per-row partial max [rt][wp][row]
  __shared__ float pl_s[2][2][16];     // per-row partial sum
  __shared__ float m_s[32];            // running row max
  __shared__ float l_s[32];            // running row denom
  __shared__ float a_s[32];            // per-iter rescale alpha
  __shared__ float rec_s[32];          // final pmask/l
  __shared__ int   nt_s;               // valid h-tile count
  __shared__ __align__(16) f16 Pt[32][72];  // P~ tile, +8 f16 pad

  const float* hm = HM + (size_t)b * NH;

  // ---- stage Q tile into LDS (fp32 -> f16 * SCALE), 16B-chunk XOR swizzle ----
  {
    const float* Qb = Q + ((size_t)b * NP + p0) * ND;
#pragma unroll
    for (int i = 0; i < 16; ++i) {
      const int g = (i << 8) + tid;    // chunk id 0..4095 (8 f16 each)
      const int r = g >> 7;            // row 0..31
      const int c = g & 127;           // chunk-in-row
      f32x4 x = *(const f32x4*)(Qb + (size_t)r * ND + (c << 3));
      f32x4 y = *(const f32x4*)(Qb + (size_t)r * ND + (c << 3) + 4);
      f16x8 hv;
      hv[0] = (f16)(x[0] * SCALE); hv[1] = (f16)(x[1] * SCALE);
      hv[2] = (f16)(x[2] * SCALE); hv[3] = (f16)(x[3] * SCALE);
      hv[4] = (f16)(y[0] * SCALE); hv[5] = (f16)(y[1] * SCALE);
      hv[6] = (f16)(y[2] * SCALE); hv[7] = (f16)(y[3] * SCALE);
      *(f16x8*)&Qs[(r << 10) + ((c ^ (r & 7)) << 3)] = hv;
    }
  }
  if (tid < 32) { m_s[tid] = -1e30f; l_s[tid] = 0.0f; }
  // ---- valid h-tile count via ballot (hm monotone, len >= NH/2) ----
  if (w == 0) {
    const int idx = (lane < 32) ? (lane << 6) : 0;   // lanes>=32 read hm[0]==1
    unsigned long long bal = __ballot(hm[idx] != 0.0f);
    if (lane == 0) nt_s = __popcll(bal) - 32;
  }
  __syncthreads();
  const int ntiles = nt_s;

  // O accumulator: wave w owns d-cols [w*256, w*256+256)
  f32x4 Oacc[2][16];
#pragma unroll
  for (int r2 = 0; r2 < 2; ++r2)
#pragma unroll
    for (int t = 0; t < 16; ++t)
      Oacc[r2][t] = (f32x4){0.f, 0.f, 0.f, 0.f};

  const f16* Kb = KVh + (size_t)b * NH * ND;
  const f16* Vt = KVt + (size_t)b * ND * NH;
  const int dbase = w << 8;
  const int ar = rt * 16 + c16;        // phase-A A-frag row
  const int rx = ar & 7;               // swizzle key

#pragma unroll 1
  for (int it = 0; it < ntiles; ++it) {
    const int h0 = it << 6;
    // ---------- Phase A: S = Q K^T ----------
    f32x4 S0 = {0.f,0.f,0.f,0.f}, S1 = {0.f,0.f,0.f,0.f};
    const f16* kr0 = Kb + (size_t)(h0 + wp * 32 + c16) * ND + (qd << 3);
    const f16* kr1 = kr0 + (size_t)16 * ND;
#pragma unroll 4
    for (int kc = 0; kc < 32; ++kc) {
      f16x8 af = *(const f16x8*)&Qs[(ar << 10) + ((((kc << 2) + qd) ^ rx) << 3)];
      f16x8 b0 = *(const f16x8*)(kr0 + (kc << 5));
      f16x8 b1 = *(const f16x8*)(kr1 + (kc << 5));
      S0 = __builtin_amdgcn_mfma_f32_16x16x32_f16(af, b0, S0, 0, 0, 0);
      S1 = __builtin_amdgcn_mfma_f32_16x16x32_f16(af, b1, S1, 0, 0, 0);
    }

    // ---------- Online softmax over valid cols (Q pre-scaled) ----------
    const float km0 = hm[h0 + wp * 32 + c16];
    const float km1 = hm[h0 + wp * 32 + 16 + c16];
    float sm0[4], sm1[4], mx[4];
#pragma unroll
    for (int rg = 0; rg < 4; ++rg) {
      sm0[rg] = (km0 != 0.f) ? S0[rg] : -1e30f;
      sm1[rg] = (km1 != 0.f) ? S1[rg] : -1e30f;
      mx[rg] = fmaxf(sm0[rg], sm1[rg]);
    }
#pragma unroll
    for (int sh = 1; sh < 16; sh <<= 1)
#pragma unroll
      for (int rg = 0; rg < 4; ++rg)
        mx[rg] = fmaxf(mx[rg], __shfl_xor(mx[rg], sh));
    if (c16 == 0) {
#pragma unroll
      for (int rg = 0; rg < 4; ++rg) pm_s[rt][wp][qd*4+rg] = mx[rg];
    }
    __syncthreads();
    if (wp == 0 && c16 == 0) {           // waves 0/1 own rows 0-15 / 16-31
#pragma unroll
      for (int rg = 0; rg < 4; ++rg) {
        const int rr = qd*4+rg, r = rt*16+rr;
        const float mt = fmaxf(pm_s[rt][0][rr], pm_s[rt][1][rr]);
        const float mo = m_s[r];
        const float mn = fmaxf(mo, mt);
        a_s[r] = __expf(mo - mn);
        m_s[r] = mn;
      }
    }
    __syncthreads();

    float ls[4] = {0.f,0.f,0.f,0.f};
#pragma unroll
    for (int rg = 0; rg < 4; ++rg) {
      const int row = rt*16 + qd*4 + rg;
      const float mn = m_s[row];
      const float pv0 = km0 * __expf(sm0[rg] - mn);
      const float pv1 = km1 * __expf(sm1[rg] - mn);
      Pt[row][wp*32 + c16]      = (f16)pv0;
      Pt[row][wp*32 + 16 + c16] = (f16)pv1;
      ls[rg] = pv0 + pv1;
    }
#pragma unroll
    for (int sh = 1; sh < 16; sh <<= 1)
#pragma unroll
      for (int rg = 0; rg < 4; ++rg)
        ls[rg] += __shfl_xor(ls[rg], sh);
    if (c16 == 0) {
#pragma unroll
      for (int rg = 0; rg < 4; ++rg) pl_s[rt][wp][qd*4+rg] = ls[rg];
    }
    __syncthreads();                     // Pt + pl complete
    if (wp == 0 && c16 == 0) {
#pragma unroll
      for (int rg = 0; rg < 4; ++rg) {
        const int rr = qd*4+rg, r = rt*16+rr;
        l_s[r] = l_s[r] * a_s[r] + pl_s[rt][0][rr] + pl_s[rt][1][rr];
      }
    }

    // ---------- Phase C: O = O*alpha + P~ V ; wave owns d-slice [w*256,+256) ----------
#pragma unroll
    for (int r2 = 0; r2 < 2; ++r2) {
      float av[4];
#pragma unroll
      for (int rg = 0; rg < 4; ++rg) av[rg] = a_s[r2*16 + qd*4 + rg];
#pragma unroll
      for (int t = 0; t < 16; ++t)
#pragma unroll
        for (int rg = 0; rg < 4; ++rg) Oacc[r2][t][rg] *= av[rg];
    }
#pragma unroll
    for (int kc2 = 0; kc2 < 2; ++kc2) {
      f16x8 pa0 = *(const f16x8*)&Pt[c16][kc2*32 + qd*8];
      f16x8 pa1 = *(const f16x8*)&Pt[16 + c16][kc2*32 + qd*8];
      // V^T frag: row d = dbase + t*16 + c16, 8 contiguous h -> ONE 16B load
      const f16* vrow = Vt + (size_t)(dbase + c16) * NH + h0 + kc2*32 + (qd << 3);
#pragma unroll
      for (int t = 0; t < 16; ++t) {   // FULL unroll: Oacc must stay in registers
        f16x8 vb = *(const f16x8*)(vrow + (size_t)t * 16 * NH);
        Oacc[0][t] = __builtin_amdgcn_mfma_f32_16x16x32_f16(pa0, vb, Oacc[0][t], 0, 0, 0);
        Oacc[1][t] = __builtin_amdgcn_mfma_f32_16x16x32_f16(pa1, vb, Oacc[1][t], 0, 0, 0);
      }
    }
    __syncthreads();                     // protect Pt/a_s before next iteration
  }

  // ---------- Epilogue: out = O / l * premise_mask ----------
  if (tid < 32) rec_s[tid] = PM[(size_t)b * NP + p0 + tid] / (l_s[tid] + 1e-13f);
  __syncthreads();
#pragma unroll
  for (int r2 = 0; r2 < 2; ++r2) {
    float rv[4];
#pragma unroll
    for (int rg = 0; rg < 4; ++rg) rv[rg] = rec_s[r2*16 + qd*4 + rg];
#pragma unroll
    for (int t = 0; t < 16; ++t) {
      float* op = OUT + ((size_t)b * NP + p0 + r2*16 + qd*4) * ND + (w << 8) + t*16 + c16;
#pragma unroll
      for (int rg = 0; rg < 4; ++rg)
        op[(size_t)rg * ND] = Oacc[r2][t][rg] * rv[rg];
    }
  }
}

extern "C" void kernel_launch(void* const* d_in, const int* in_sizes, int n_in,
                              void* d_out, int out_size, void* d_ws, size_t ws_size,
                              hipStream_t stream) {
  const float* Q  = (const float*)d_in[0];  // premise_batch   [16][2048][1024]
  const float* PM = (const float*)d_in[1];  // premise_mask    [16][2048]
  const float* KV = (const float*)d_in[2];  // hypothesis_batch[16][2048][1024]
  const float* HM = (const float*)d_in[3];  // hypothesis_mask [16][2048]
  float* OUT = (float*)d_out;               // [16][2048][1024] fp32

  // workspace: KVh (64MB) + KVt (64MB) = 128MB f16 copies of hypothesis
  f16* KVh = (f16*)d_ws;
  f16* KVt = KVh + (size_t)NB * NH * ND;
  (void)ws_size; (void)in_sizes; (void)n_in; (void)out_size;

  dim3 pgrid(ND / 64, NH / 64, NB);         // 8192 blocks
  hipLaunchKernelGGL(prep, pgrid, dim3(256), 0, stream, KV, KVh, KVt);

  dim3 grid(NB * (NP / MT));                // 1024 blocks
  hipLaunchKernelGGL(uniattn, grid, dim3(256), 0, stream, Q, PM, KVh, KVt, HM, OUT);
}